// Round 18
// baseline (1461.028 us; speedup 1.0000x reference)
//
#include <hip/hip_runtime.h>
#include <hip/hip_bf16.h>

#define D_MODEL 512
#define NHEAD   8
#define DHEAD   64
#define SEQ     1024
#define NBATCH  8
#define NTOK    8192
#define DFF_N   2048
#define NLAYER  8
#define VOCAB   258
#define VPAD    384

typedef float f32x4 __attribute__((ext_vector_type(4)));
typedef short s16x8 __attribute__((ext_vector_type(8)));

__device__ __forceinline__ ushort f2b(float f) {
    union { float f; unsigned u; } v; v.f = f;
    unsigned r = (v.u + 0x7fffu + ((v.u >> 16) & 1u)) >> 16;
    return (ushort)r;
}
__device__ __forceinline__ float gelu_f(float x) {
    return 0.5f * x * (1.0f + erff(x * 0.70710678118654752f));
}
__device__ __forceinline__ void gl_lds16(const void* g, void* l) {
    __builtin_amdgcn_global_load_lds(
        (const __attribute__((address_space(1))) void*)g,
        (__attribute__((address_space(3))) void*)l, 16, 0, 0);
}
__device__ __forceinline__ float exp2_fast(float x) {
    float r; asm("v_exp_f32 %0, %1" : "=v"(r) : "v"(x)); return r;
}
__device__ __forceinline__ unsigned cvtpk(float lo, float hi) {
    unsigned r; asm("v_cvt_pk_bf16_f32 %0, %1, %2" : "=v"(r) : "v"(lo), "v"(hi)); return r;
}

// ---------------- f32 -> bf16 convert (single region) ----------------
__global__ __launch_bounds__(256) void cvt_bf16(
    const float* __restrict__ in, ushort* __restrict__ out, int n)
{
    int i = (blockIdx.x * 256 + threadIdx.x) << 2;
    if (i >= n) return;
    float4 v = *(const float4*)(in + i);
    ushort4 o;
    o.x = f2b(v.x); o.y = f2b(v.y); o.z = f2b(v.z); o.w = f2b(v.w);
    *(ushort4*)(out + i) = o;
}

// ---------------- per-layer 4-region weight convert (1 launch) ----------------
__global__ __launch_bounds__(256) void cvt_layer(
    const float* __restrict__ s0, const float* __restrict__ s1,
    const float* __restrict__ s2, const float* __restrict__ s3,
    ushort* __restrict__ d0, ushort* __restrict__ d1,
    ushort* __restrict__ d2, ushort* __restrict__ d3)
{
    int i = (blockIdx.x * 256 + threadIdx.x) << 2;
    const float* s; ushort* d; int off;
    if (i < 786432)        { s = s0; d = d0; off = i; }
    else if (i < 1048576)  { s = s1; d = d1; off = i - 786432; }
    else if (i < 2097152)  { s = s2; d = d2; off = i - 1048576; }
    else                   { s = s3; d = d3; off = i - 2097152; }
    float4 v = *(const float4*)(s + off);
    ushort4 o;
    o.x = f2b(v.x); o.y = f2b(v.y); o.z = f2b(v.z); o.w = f2b(v.w);
    *(ushort4*)(d + off) = o;
}

// ---------------- entropy features + embedding (f32 out) ----------------
__global__ __launch_bounds__(128) void embed_kernel(
    const int* __restrict__ x, const float* __restrict__ embed,
    const float* __restrict__ ep_w, const float* __restrict__ ep_b,
    float* __restrict__ h)
{
    int t = blockIdx.x;
    int pos = t & (SEQ - 1);
    float ent = 0.0f;
    if (pos <= SEQ - 8) {
        int v[8];
        #pragma unroll
        for (int i = 0; i < 8; i++) v[i] = x[t + i];
        float s = 0.0f;
        #pragma unroll
        for (int i = 0; i < 8; i++) {
            int c = 0;
            #pragma unroll
            for (int j = 0; j < 8; j++) c += (v[j] == v[i]) ? 1 : 0;
            s += log2f((float)c);
        }
        ent = 3.0f - 0.125f * s;
    }
    int tok = x[t];
    int d = threadIdx.x << 2;
    float e[4], w[4], bb[4], r[4];
    *(float4*)e  = *(const float4*)(embed + (size_t)tok * D_MODEL + d);
    *(float4*)w  = *(const float4*)(ep_w + d);
    *(float4*)bb = *(const float4*)(ep_b + d);
    #pragma unroll
    for (int j = 0; j < 4; j++) r[j] = e[j] + ent * w[j] + bb[j];
    *(float4*)(h + (size_t)t * D_MODEL + d) = *(float4*)r;
}

// ---------------- LayerNorm: f32 in -> bf16 out ----------------
__global__ __launch_bounds__(256) void ln_kernel(
    const float* __restrict__ in, const float* __restrict__ w,
    const float* __restrict__ b, ushort* __restrict__ out)
{
    int wid = threadIdx.x >> 6, lane = threadIdx.x & 63;
    int t = (blockIdx.x << 2) + wid;
    const float* row = in + (size_t)t * D_MODEL;
    float a[8];
    *(float4*)(a)     = *(const float4*)(row + (lane << 2));
    *(float4*)(a + 4) = *(const float4*)(row + 256 + (lane << 2));
    float s = 0.f;
    #pragma unroll
    for (int j = 0; j < 8; j++) s += a[j];
    #pragma unroll
    for (int o = 1; o < 64; o <<= 1) s += __shfl_xor(s, o);
    float mu = s * (1.0f / 512.0f);
    float vs = 0.f;
    #pragma unroll
    for (int j = 0; j < 8; j++) { float d0 = a[j] - mu; vs += d0 * d0; }
    #pragma unroll
    for (int o = 1; o < 64; o <<= 1) vs += __shfl_xor(vs, o);
    float inv = rsqrtf(vs * (1.0f / 512.0f) + 1e-5f);
    float ww[8], bbv[8];
    *(float4*)(ww)      = *(const float4*)(w + (lane << 2));
    *(float4*)(ww + 4)  = *(const float4*)(w + 256 + (lane << 2));
    *(float4*)(bbv)     = *(const float4*)(b + (lane << 2));
    *(float4*)(bbv + 4) = *(const float4*)(b + 256 + (lane << 2));
    ushort* orow = out + (size_t)t * D_MODEL;
    ushort4 o1, o2;
    o1.x = f2b((a[0] - mu) * inv * ww[0] + bbv[0]);
    o1.y = f2b((a[1] - mu) * inv * ww[1] + bbv[1]);
    o1.z = f2b((a[2] - mu) * inv * ww[2] + bbv[2]);
    o1.w = f2b((a[3] - mu) * inv * ww[3] + bbv[3]);
    o2.x = f2b((a[4] - mu) * inv * ww[4] + bbv[4]);
    o2.y = f2b((a[5] - mu) * inv * ww[5] + bbv[5]);
    o2.z = f2b((a[6] - mu) * inv * ww[6] + bbv[6]);
    o2.w = f2b((a[7] - mu) * inv * ww[7] + bbv[7]);
    *(ushort4*)(orow + (lane << 2))       = o1;
    *(ushort4*)(orow + 256 + (lane << 2)) = o2;
}

// ---------------- bf16 MFMA GEMM, BN in {128,64}, BK=32 (round-16) ----------
// 3-buffer counted-vmcnt pipeline + chunk-XOR swizzle + T1 XCD remap.
template<int BN>
__global__ __launch_bounds__(256) void gemm_t(
    const ushort* __restrict__ A, const ushort* __restrict__ Bw,
    const float* __restrict__ bias, const float* __restrict__ resid,
    float* __restrict__ Cf, ushort* __restrict__ Cb, ushort* __restrict__ Vtr,
    int M, int N, int K, int fuse)
{
    constexpr int NF = BN / 32;
    constexpr int EPW = BN + 4;
    __shared__ ushort SMEM[3 * 4096 + 3 * BN * 32];
    ushort* As0 = SMEM;                         // [3][4096]
    ushort* Bs0 = SMEM + 12288;                 // [3][BN*32]
    const int tid = threadIdx.x;
    const int l = tid & 63, w = tid >> 6;
    const int p  = blockIdx.y * gridDim.x + blockIdx.x;
    const int bx = ((p & 7) << 3) + ((p >> 3) & 7);
    const int by = p >> 6;
    const int m0 = bx << 7, n0 = by * BN;
    const int wrn = (w >> 1) << 6;
    const int wcn = (w & 1) * (BN / 2);
    const int fm = l & 15;
    const int soff = (((l & 3) ^ ((l >> 3) & 3)) << 3);
    const int foff = (((l >> 4) ^ ((fm >> 1) & 3)) << 3);
    f32x4 acc[4][NF] = {};

    const ushort* ga0 = A + (size_t)(m0 + (w << 5) + (l >> 2)) * K + soff;
    const ushort* ga1 = ga0 + (size_t)16 * K;
    const ushort* gb0;
    const ushort* gb1 = nullptr;
    if constexpr (BN == 128) {
        gb0 = Bw + (size_t)(n0 + (w << 5) + (l >> 2)) * K + soff;
        gb1 = gb0 + (size_t)16 * K;
    } else {
        gb0 = Bw + (size_t)(n0 + (w << 4) + (l >> 2)) * K + soff;
    }

    const int nk = K >> 5;
    auto stage = [&](int buf, int ko) {
        gl_lds16(ga0 + ko, As0 + buf * 4096 + (w << 10));
        gl_lds16(ga1 + ko, As0 + buf * 4096 + (w << 10) + 512);
        if constexpr (BN == 128) {
            gl_lds16(gb0 + ko, Bs0 + buf * (BN * 32) + (w << 10));
            gl_lds16(gb1 + ko, Bs0 + buf * (BN * 32) + (w << 10) + 512);
        } else {
            gl_lds16(gb0 + ko, Bs0 + buf * (BN * 32) + (w << 9));
        }
    };

    stage(0, 0);
    stage(1, 32);
    int cur = 0;
    for (int kt = 0; kt < nk; ++kt) {
        if (kt + 1 < nk) {
            if constexpr (BN == 128) asm volatile("s_waitcnt vmcnt(4)" ::: "memory");
            else                     asm volatile("s_waitcnt vmcnt(3)" ::: "memory");
        } else {
            asm volatile("s_waitcnt vmcnt(0)" ::: "memory");
        }
        asm volatile("s_barrier" ::: "memory");
        __builtin_amdgcn_sched_barrier(0);
        {
            int nxt = cur + 2; if (nxt >= 3) nxt -= 3;
            if (kt + 2 < nk) stage(nxt, (kt + 2) << 5);
        }
        s16x8 af[4], bf[NF];
        #pragma unroll
        for (int x = 0; x < 4; ++x)
            af[x] = *(const s16x8*)&As0[cur * 4096 + (wrn + (x << 4) + fm) * 32 + foff];
        #pragma unroll
        for (int y = 0; y < NF; ++y)
            bf[y] = *(const s16x8*)&Bs0[cur * (BN * 32) + (wcn + (y << 4) + fm) * 32 + foff];
        #pragma unroll
        for (int x = 0; x < 4; ++x)
            #pragma unroll
            for (int y = 0; y < NF; ++y)
                acc[x][y] = __builtin_amdgcn_mfma_f32_16x16x32_bf16(
                    af[x], bf[y], acc[x][y], 0, 0, 0);
        cur = (cur == 2) ? 0 : cur + 1;
    }
    __syncthreads();

    const float qs = (Vtr && n0 < 512) ? 0.18033688011112042f : 1.0f;
    const bool vblk = (Vtr != nullptr) && (n0 >= 1024);

    if (Cb != nullptr || vblk) {
        float* Ep = (float*)SMEM;
        const int lrw = ((w >> 1) << 4) + ((l >> 4) << 2);
        #pragma unroll
        for (int x = 0; x < 4; ++x) {
            __syncthreads();
            #pragma unroll
            for (int y = 0; y < NF; ++y) {
                const int c = wcn + (y << 4) + fm;
                const float bv = bias ? bias[n0 + c] : 0.f;
                #pragma unroll
                for (int i = 0; i < 4; ++i) {
                    float v = acc[x][y][i] + bv;
                    v *= qs;
                    if (fuse == 1) v = gelu_f(v);
                    Ep[(lrw + i) * EPW + c] = v;
                }
            }
            __syncthreads();
            if (vblk) {
                const int c = tid & 127;
                const int run = tid >> 7;
                const int colg = (n0 - 1024) + c;
                const int hh = colg >> 6, dd = colg & 63;
                float v16[16];
                #pragma unroll
                for (int j = 0; j < 16; ++j)
                    v16[j] = Ep[((run << 4) + j) * EPW + c];
                unsigned pk[8];
                #pragma unroll
                for (int j = 0; j < 8; ++j) pk[j] = cvtpk(v16[2 * j], v16[2 * j + 1]);
                ushort* dst = Vtr + ((size_t)(((m0 >> 10) << 3) + hh) * 64 + dd) * 1024
                              + (m0 & 1023) + (run << 6) + (x << 4);
                *(uint4*)dst       = *(uint4*)(pk);
                *(uint4*)(dst + 8) = *(uint4*)(pk + 4);
            } else {
                constexpr int TPR = BN / 8;
                constexpr int RPP = 256 / TPR;
                constexpr int NP = 32 / RPP;
                #pragma unroll
                for (int p2 = 0; p2 < NP; ++p2) {
                    const int lr = p2 * RPP + (tid / TPR);
                    const int cg = (tid % TPR) << 3;
                    const int grow = m0 + ((lr >> 4) << 6) + (x << 4) + (lr & 15);
                    const int gcol = n0 + cg;
                    float v8[8];
                    *(float4*)(v8)     = *(float4*)&Ep[lr * EPW + cg];
                    *(float4*)(v8 + 4) = *(float4*)&Ep[lr * EPW + cg + 4];
                    if (fuse == 2) {
                        float4 r1 = *(const float4*)&resid[(size_t)grow * N + gcol];
                        float4 r2 = *(const float4*)&resid[(size_t)grow * N + gcol + 4];
                        v8[0] += r1.x; v8[1] += r1.y; v8[2] += r1.z; v8[3] += r1.w;
                        v8[4] += r2.x; v8[5] += r2.y; v8[6] += r2.z; v8[7] += r2.w;
                    }
                    if (Cf) {
                        *(float4*)&Cf[(size_t)grow * N + gcol]     = *(float4*)v8;
                        *(float4*)&Cf[(size_t)grow * N + gcol + 4] = *(float4*)(v8 + 4);
                    }
                    unsigned pk[4];
                    pk[0] = cvtpk(v8[0], v8[1]); pk[1] = cvtpk(v8[2], v8[3]);
                    pk[2] = cvtpk(v8[4], v8[5]); pk[3] = cvtpk(v8[6], v8[7]);
                    *(uint4*)&Cb[(size_t)grow * N + gcol] = *(uint4*)pk;
                }
            }
        }
        return;
    }

    const int col0 = n0 + wcn + fm;
    const int row0 = m0 + wrn + ((l >> 4) << 2);
    #pragma unroll
    for (int x = 0; x < 4; ++x) {
        #pragma unroll
        for (int y = 0; y < NF; ++y) {
            int col = col0 + (y << 4);
            if (col >= N) continue;
            float bv = bias ? bias[col] : 0.f;
            #pragma unroll
            for (int i = 0; i < 4; ++i) {
                int row = row0 + (x << 4) + i;
                float v = acc[x][y][i] + bv;
                if (fuse == 1) v = gelu_f(v);
                else if (fuse == 2) v += resid[(size_t)row * N + col];
                Cf[(size_t)row * N + col] = v;
            }
        }
    }
}

// ---------------- bf16 MFMA GEMM, BM=128 x BN=256 x BK=32 ----------------
// For f1 (N=2048): wave tile 64x128 (acc[4][8]) -> 12 b128 reads feed 32 MFMA
// (ratio 2.67 vs 2.0), attacking the measured LDS-read-throughput wall.
// Grid (64,8)=512 = 2 blocks/CU = exactly the 72KB 3-buffer LDS cap.
// Counted vmcnt(6) (6 loads/stage, 2 stages in flight); same swizzle/remap.
__global__ __launch_bounds__(256) void gemm_n256(
    const ushort* __restrict__ A, const ushort* __restrict__ Bw,
    const float* __restrict__ bias,
    float* __restrict__ Cf, ushort* __restrict__ Cb,
    int M, int N, int K, int fuse)
{
    constexpr int EPW = 260;
    __shared__ ushort SMEM[3 * 4096 + 3 * 8192];   // A [3][128*32] | B [3][256*32]
    ushort* As0 = SMEM;
    ushort* Bs0 = SMEM + 12288;
    const int tid = threadIdx.x;
    const int l = tid & 63, w = tid >> 6;
    const int p  = blockIdx.y * gridDim.x + blockIdx.x;
    const int bx = ((p & 7) << 3) + ((p >> 3) & 7);
    const int by = p >> 6;
    const int m0 = bx << 7, n0 = by << 8;
    const int wrn = (w >> 1) << 6;     // wave rows: 64
    const int wcn = (w & 1) << 7;      // wave cols: 128
    const int fm = l & 15;
    const int soff = (((l & 3) ^ ((l >> 3) & 3)) << 3);
    const int foff = (((l >> 4) ^ ((fm >> 1) & 3)) << 3);
    f32x4 acc[4][8] = {};

    const ushort* ga0 = A + (size_t)(m0 + (w << 5) + (l >> 2)) * K + soff;
    const ushort* ga1 = ga0 + (size_t)16 * K;
    const ushort* gb0 = Bw + (size_t)(n0 + (w << 6) + (l >> 2)) * K + soff;
    const ushort* gb1 = gb0 + (size_t)16 * K;
    const ushort* gb2 = gb0 + (size_t)32 * K;
    const ushort* gb3 = gb0 + (size_t)48 * K;

    const int nk = K >> 5;
    auto stage = [&](int buf, int ko) {
        gl_lds16(ga0 + ko, As0 + buf * 4096 + (w << 10));
        gl_lds16(ga1 + ko, As0 + buf * 4096 + (w << 10) + 512);
        gl_lds16(gb0 + ko, Bs0 + buf * 8192 + (w << 11));
        gl_lds16(gb1 + ko, Bs0 + buf * 8192 + (w << 11) + 512);
        gl_lds16(gb2 + ko, Bs0 + buf * 8192 + (w << 11) + 1024);
        gl_lds16(gb3 + ko, Bs0 + buf * 8192 + (w << 11) + 1536);
    };

    stage(0, 0);
    stage(1, 32);
    int cur = 0;
    for (int kt = 0; kt < nk; ++kt) {
        if (kt + 1 < nk) asm volatile("s_waitcnt vmcnt(6)" ::: "memory");
        else             asm volatile("s_waitcnt vmcnt(0)" ::: "memory");
        asm volatile("s_barrier" ::: "memory");
        __builtin_amdgcn_sched_barrier(0);
        {
            int nxt = cur + 2; if (nxt >= 3) nxt -= 3;
            if (kt + 2 < nk) stage(nxt, (kt + 2) << 5);
        }
        s16x8 af[4], bf[8];
        #pragma unroll
        for (int x = 0; x < 4; ++x)
            af[x] = *(const s16x8*)&As0[cur * 4096 + (wrn + (x << 4) + fm) * 32 + foff];
        #pragma unroll
        for (int y = 0; y < 8; ++y)
            bf[y] = *(const s16x8*)&Bs0[cur * 8192 + (wcn + (y << 4) + fm) * 32 + foff];
        #pragma unroll
        for (int x = 0; x < 4; ++x)
            #pragma unroll
            for (int y = 0; y < 8; ++y)
                acc[x][y] = __builtin_amdgcn_mfma_f32_16x16x32_bf16(
                    af[x], bf[y], acc[x][y], 0, 0, 0);
        cur = (cur == 2) ? 0 : cur + 1;
    }
    __syncthreads();

    // -------- LDS-transpose epilogue (coalesced bf16 stores) --------
    float* Ep = (float*)SMEM;                   // 32 x 260 f32 = 33KB
    const int lrw = ((w >> 1) << 4) + ((l >> 4) << 2);
    #pragma unroll                              // CRITICAL: static acc indexing
    for (int x = 0; x < 4; ++x) {
        __syncthreads();
        #pragma unroll
        for (int y = 0; y < 8; ++y) {
            const int c = wcn + (y << 4) + fm;
            const float bv = bias ? bias[n0 + c] : 0.f;
            #pragma unroll
            for (int i = 0; i < 4; ++i) {
                float v = acc[x][y][i] + bv;
                if (fuse == 1) v = gelu_f(v);
                Ep[(lrw + i) * EPW + c] = v;
            }
        }
        __syncthreads();
        // 256 threads: 32 thr/row x 8 rows/pass x 4 passes
        #pragma unroll
        for (int p2 = 0; p2 < 4; ++p2) {
            const int lr = p2 * 8 + (tid >> 5);
            const int cg = (tid & 31) << 3;
            const int grow = m0 + ((lr >> 4) << 6) + (x << 4) + (lr & 15);
            const int gcol = n0 + cg;
            float v8[8];
            *(float4*)(v8)     = *(float4*)&Ep[lr * EPW + cg];
            *(float4*)(v8 + 4) = *(float4*)&Ep[lr * EPW + cg + 4];
            if (Cf) {
                *(float4*)&Cf[(size_t)grow * N + gcol]     = *(float4*)v8;
                *(float4*)&Cf[(size_t)grow * N + gcol + 4] = *(float4*)(v8 + 4);
            }
            unsigned pk[4];
            pk[0] = cvtpk(v8[0], v8[1]); pk[1] = cvtpk(v8[2], v8[3]);
            pk[2] = cvtpk(v8[4], v8[5]); pk[3] = cvtpk(v8[6], v8[7]);
            *(uint4*)&Cb[(size_t)grow * N + gcol] = *(uint4*)pk;
        }
    }
}

// ---------------- bf16 MFMA GEMM, BM=128 x BN=64 x BK=64 (round-17) --------
__global__ __launch_bounds__(256) void gemm_k64(
    const ushort* __restrict__ A, const ushort* __restrict__ Bw,
    const float* __restrict__ bias, const float* __restrict__ resid,
    float* __restrict__ Cf, ushort* __restrict__ Cb,
    int M, int N, int K, int fuse)
{
    constexpr int EPW = 68;
    __shared__ ushort SMEM[3 * 8192 + 3 * 4096];
    ushort* As0 = SMEM;
    ushort* Bs0 = SMEM + 24576;
    const int tid = threadIdx.x;
    const int l = tid & 63, w = tid >> 6;
    const int p  = blockIdx.y * gridDim.x + blockIdx.x;
    const int bx = ((p & 7) << 3) + ((p >> 3) & 7);
    const int by = p >> 6;
    const int m0 = bx << 7, n0 = by << 6;
    const int wrn = (w >> 1) << 6;
    const int wcn = (w & 1) << 5;
    const int fm = l & 15, fk = l >> 4;
    f32x4 acc[4][2] = {};

    const int srow = (w << 3) + (l >> 3);
    const int cch = ((l & 7) ^ (l >> 3)) << 3;
    const ushort* gaP0 = A + (size_t)(m0 + srow) * K + cch;
    const ushort* gbP0 = Bw + (size_t)(n0 + srow) * K + cch;

    const int foff0 = (((0 << 2) + fk) ^ (fm & 7)) << 3;
    const int foff1 = (((1 << 2) + fk) ^ (fm & 7)) << 3;

    const int nk = K >> 6;
    auto stage = [&](int buf, int ko) {
        #pragma unroll
        for (int p2 = 0; p2 < 4; ++p2)
            gl_lds16(gaP0 + (size_t)(p2 << 5) * K + ko,
                     As0 + buf * 8192 + (p2 << 11) + (w << 9));
        #pragma unroll
        for (int p2 = 0; p2 < 2; ++p2)
            gl_lds16(gbP0 + (size_t)(p2 << 5) * K + ko,
                     Bs0 + buf * 4096 + (p2 << 11) + (w << 9));
    };

    stage(0, 0);
    stage(1, 64);
    int cur = 0;
    for (int kt = 0; kt < nk; ++kt) {
        if (kt + 1 < nk) asm volatile("s_waitcnt vmcnt(6)" ::: "memory");
        else             asm volatile("s_waitcnt vmcnt(0)" ::: "memory");
        asm volatile("s_barrier" ::: "memory");
        __builtin_amdgcn_sched_barrier(0);
        {
            int nxt = cur + 2; if (nxt >= 3) nxt -= 3;
            if (kt + 2 < nk) stage(nxt, (kt + 2) << 6);
        }
        {
            s16x8 af[4], bf[2];
            #pragma unroll
            for (int x = 0; x < 4; ++x)
                af[x] = *(const s16x8*)&As0[cur * 8192 + (wrn + (x << 4) + fm) * 64 + foff0];
            #pragma unroll
            for (int y = 0; y < 2; ++y)
                bf[y] = *(const s16x8*)&Bs0[cur * 4096 + (wcn + (y << 4) + fm) * 64 + foff0];
            #pragma unroll
            for (int x = 0; x < 4; ++x)
                #pragma unroll
                for (int y = 0; y < 2; ++y)
                    acc[x][y] = __builtin_amdgcn_mfma_f32_16x16x32_bf16(
                        af[x], bf[y], acc[x][y], 0, 0, 0);
        }
        {
            s16x8 af[4], bf[2];
            #pragma unroll
            for (int x = 0; x < 4; ++x)
                af[x] = *(const s16x8*)&As0[cur * 8192 + (wrn + (x << 4) + fm) * 64 + foff1];
            #pragma unroll
            for (int y = 0; y < 2; ++y)
                bf[y] = *(const s16x8*)&Bs0[cur * 4096 + (wcn + (y << 4) + fm) * 64 + foff1];
            #pragma unroll
            for (int x = 0; x < 4; ++x)
                #pragma unroll
                for (int y = 0; y < 2; ++y)
                    acc[x][y] = __builtin_amdgcn_mfma_f32_16x16x32_bf16(
                        af[x], bf[y], acc[x][y], 0, 0, 0);
        }
        cur = (cur == 2) ? 0 : cur + 1;
    }
    __syncthreads();

    if (Cb != nullptr) {
        float* Ep = (float*)SMEM;
        const int lrw = ((w >> 1) << 4) + ((l >> 4) << 2);
        #pragma unroll
        for (int x = 0; x < 4; ++x) {
            __syncthreads();
            #pragma unroll
            for (int y = 0; y < 2; ++y) {
                const int c = wcn + (y << 4) + fm;
                const float bv = bias ? bias[n0 + c] : 0.f;
                #pragma unroll
                for (int i = 0; i < 4; ++i) {
                    float v = acc[x][y][i] + bv;
                    if (fuse == 1) v = gelu_f(v);
                    Ep[(lrw + i) * EPW + c] = v;
                }
            }
            __syncthreads();
            {
                const int lr = tid >> 3;
                const int cg = (tid & 7) << 3;
                const int grow = m0 + ((lr >> 4) << 6) + (x << 4) + (lr & 15);
                const int gcol = n0 + cg;
                float v8[8];
                *(float4*)(v8)     = *(float4*)&Ep[lr * EPW + cg];
                *(float4*)(v8 + 4) = *(float4*)&Ep[lr * EPW + cg + 4];
                if (fuse == 2) {
                    float4 r1 = *(const float4*)&resid[(size_t)grow * N + gcol];
                    float4 r2 = *(const float4*)&resid[(size_t)grow * N + gcol + 4];
                    v8[0] += r1.x; v8[1] += r1.y; v8[2] += r1.z; v8[3] += r1.w;
                    v8[4] += r2.x; v8[5] += r2.y; v8[6] += r2.z; v8[7] += r2.w;
                }
                if (Cf) {
                    *(float4*)&Cf[(size_t)grow * N + gcol]     = *(float4*)v8;
                    *(float4*)&Cf[(size_t)grow * N + gcol + 4] = *(float4*)(v8 + 4);
                }
                unsigned pk[4];
                pk[0] = cvtpk(v8[0], v8[1]); pk[1] = cvtpk(v8[2], v8[3]);
                pk[2] = cvtpk(v8[4], v8[5]); pk[3] = cvtpk(v8[6], v8[7]);
                *(uint4*)&Cb[(size_t)grow * N + gcol] = *(uint4*)pk;
            }
        }
        return;
    }

    const int col0 = n0 + wcn + fm;
    const int row0 = m0 + wrn + ((l >> 4) << 2);
    #pragma unroll
    for (int x = 0; x < 4; ++x) {
        #pragma unroll
        for (int y = 0; y < 2; ++y) {
            int col = col0 + (y << 4);
            if (col >= N) continue;
            float bv = bias ? bias[col] : 0.f;
            #pragma unroll
            for (int i = 0; i < 4; ++i) {
                int row = row0 + (x << 4) + i;
                float v = acc[x][y][i] + bv;
                if (fuse == 1) v = gelu_f(v);
                else if (fuse == 2) v += resid[(size_t)row * N + col];
                Cf[(size_t)row * N + col] = v;
            }
        }
    }
}

// ---------------- bf16 MFMA flash attention v7 (round-14, 2-buffer) ---------
__global__ __launch_bounds__(512) void attn_mfma(
    const ushort* __restrict__ qkv, const ushort* __restrict__ vT,
    ushort* __restrict__ out)
{
    __shared__ ushort Ks[2][4096];
    __shared__ ushort Vs[2][4096];
    const int tid = threadIdx.x;
    const int l = tid & 63, w = tid >> 6;
    const int p = blockIdx.y * gridDim.x + blockIdx.x;
    const int bh = ((p & 7) << 3) + (p >> 6);
    const int q0 = ((p >> 3) & 7) << 7;
    const int b = bh >> 3, h = bh & 7;
    const ushort* base = qkv + (size_t)b * SEQ * 1536 + h * 64;
    const ushort* kg = base + 512;
    const ushort* vg = vT + ((size_t)bh << 16);
    const int fm = l & 15, fk = l >> 4;

    s16x8 qf[2];
    {
        const ushort* qrow = base + (size_t)(q0 + (w << 4) + fm) * 1536 + (fk << 3);
        qf[0] = *(const s16x8*)qrow;
        qf[1] = *(const s16x8*)(qrow + 32);
    }
    s16x8 ones_f;
    #pragma unroll
    for (int j = 0; j < 8; ++j) ones_f[j] = (short)0x3F80;

    f32x4 accO[4] = {};
    f32x4 accL = {};

    const int srow = (w << 3) + (l >> 3);
    const int cch = ((l & 7) ^ (l >> 3)) << 3;
    const ushort* kga = kg + (size_t)srow * 1536 + cch;
    const ushort* vga = vg + (size_t)srow * 1024 + cch;

    int fidx[2][4];
    #pragma unroll
    for (int ks = 0; ks < 2; ++ks)
        #pragma unroll
        for (int n = 0; n < 4; ++n)
            fidx[ks][n] = (((n << 4) + fm) << 6) + ((((ks << 2) + fk) ^ (l & 7)) << 3);

    const int srcA = ((fk & 1) << 5) + fm;
    const int srcB = srcA + 16;
    const bool hiN = (fk >> 1) != 0;

    #define STAGE(buf, kt)                                                    \
        do {                                                                  \
            gl_lds16(kga + (size_t)((kt) << 6) * 1536, &Ks[buf][w << 9]);     \
            gl_lds16(vga + ((kt) << 6), &Vs[buf][w << 9]);                    \
        } while (0)

    STAGE(0, 0);
    asm volatile("s_waitcnt vmcnt(0)" ::: "memory");
    __builtin_amdgcn_s_barrier();

    int cur = 0;
    for (int kt = 0; kt < SEQ / 64; ++kt) {
        if (kt + 1 < SEQ / 64) STAGE(cur ^ 1, kt + 1);
        __builtin_amdgcn_sched_barrier(0);

        f32x4 s[4] = {};
        __builtin_amdgcn_s_setprio(1);
        #pragma unroll
        for (int ks = 0; ks < 2; ++ks)
            #pragma unroll
            for (int n = 0; n < 4; ++n) {
                s16x8 kf = *(const s16x8*)&Ks[cur][fidx[ks][n]];
                s[n] = __builtin_amdgcn_mfma_f32_16x16x32_bf16(kf, qf[ks], s[n], 0, 0, 0);
            }
        __builtin_amdgcn_s_setprio(0);

        unsigned pk0[2], pk1[2], pk2[2], pk3[2];
        pk0[0] = cvtpk(exp2_fast(s[0][0]), exp2_fast(s[0][1]));
        pk0[1] = cvtpk(exp2_fast(s[0][2]), exp2_fast(s[0][3]));
        pk1[0] = cvtpk(exp2_fast(s[1][0]), exp2_fast(s[1][1]));
        pk1[1] = cvtpk(exp2_fast(s[1][2]), exp2_fast(s[1][3]));
        pk2[0] = cvtpk(exp2_fast(s[2][0]), exp2_fast(s[2][1]));
        pk2[1] = cvtpk(exp2_fast(s[2][2]), exp2_fast(s[2][3]));
        pk3[0] = cvtpk(exp2_fast(s[3][0]), exp2_fast(s[3][1]));
        pk3[1] = cvtpk(exp2_fast(s[3][2]), exp2_fast(s[3][3]));

        #pragma unroll
        for (int ks = 0; ks < 2; ++ks) {
            unsigned u0 = ks ? pk2[0] : pk0[0], u1 = ks ? pk2[1] : pk0[1];
            unsigned v0 = ks ? pk3[0] : pk1[0], v1 = ks ? pk3[1] : pk1[1];
            unsigned a0 = __shfl((int)u0, srcA), b0 = __shfl((int)v0, srcA);
            unsigned a1 = __shfl((int)u1, srcA), b1 = __shfl((int)v1, srcA);
            unsigned a2 = __shfl((int)u0, srcB), b2 = __shfl((int)v0, srcB);
            unsigned a3 = __shfl((int)u1, srcB), b3 = __shfl((int)v1, srcB);
            union { unsigned u[4]; s16x8 v; } pb;
            pb.u[0] = hiN ? b0 : a0;
            pb.u[1] = hiN ? b1 : a1;
            pb.u[2] = hiN ? b2 : a2;
            pb.u[3] = hiN ? b3 : a3;
            __builtin_amdgcn_s_setprio(1);
            #pragma unroll
            for (int n = 0; n < 4; ++n) {
                s16x8 vf = *(const s16x8*)&Vs[cur][fidx[ks][n]];
                accO[n] = __builtin_amdgcn_mfma_f32_16x16x32_bf16(vf, pb.v, accO[n], 0, 0, 0);
            }
            accL = __builtin_amdgcn_mfma_f32_16x16x32_bf16(ones_f, pb.v, accL, 0, 0, 0);
            __builtin_amdgcn_s_setprio(0);
        }

        asm volatile("s_waitcnt vmcnt(0)" ::: "memory");
        __builtin_amdgcn_s_barrier();
        __builtin_amdgcn_sched_barrier(0);
        cur ^= 1;
    }
    #undef STAGE

    const int q = q0 + (w << 4) + fm;
    float inv = 1.0f / accL[0];
    ushort* obase = out + ((size_t)(b * SEQ + q)) * 512 + h * 64 + (fk << 2);
    #pragma unroll
    for (int n = 0; n < 4; ++n) {
        ushort4 o;
        o.x = f2b(accO[n][0] * inv);
        o.y = f2b(accO[n][1] * inv);
        o.z = f2b(accO[n][2] * inv);
        o.w = f2b(accO[n][3] * inv);
        *(ushort4*)(obase + (n << 4)) = o;
    }
}

extern "C" void kernel_launch(void* const* d_in, const int* in_sizes, int n_in,
                              void* d_out, int out_size, void* d_ws, size_t ws_size,
                              hipStream_t stream) {
    const int*   x     = (const int*)  d_in[0];
    const float* embed = (const float*)d_in[1];
    const float* ep_w  = (const float*)d_in[2];
    const float* ep_b  = (const float*)d_in[3];
    const float* in_w  = (const float*)d_in[4];
    const float* in_b  = (const float*)d_in[5];
    const float* op_w  = (const float*)d_in[6];
    const float* op_b  = (const float*)d_in[7];
    const float* ln1_w = (const float*)d_in[8];
    const float* ln1_b = (const float*)d_in[9];
    const float* ln2_w = (const float*)d_in[10];
    const float* ln2_b = (const float*)d_in[11];
    const float* f1_w  = (const float*)d_in[12];
    const float* f1_b  = (const float*)d_in[13];
    const float* f2_w  = (const float*)d_in[14];
    const float* f2_b  = (const float*)d_in[15];
    const float* out_w = (const float*)d_in[16];
    float* out = (float*)d_out;

    char* ws = (char*)d_ws;
    float*  h    = (float*) (ws + 0);
    ushort* g    = (ushort*)(ws + 16777216);
    ushort* big  = (ushort*)(ws + 25165824);
    ushort* qkvb = big;
    ushort* hb   = (ushort*)(ws + 58720256);
    ushort* wq   = (ushort*)(ws + 67108864);
    ushort* wo   = (ushort*)(ws + 68681728);
    ushort* w1   = (ushort*)(ws + 69206016);
    ushort* w2   = (ushort*)(ws + 71303168);
    ushort* wv   = (ushort*)(ws + 73400320);
    ushort* vT   = (ushort*)(ws + 73793536);

    hipMemsetAsync(wv, 0, (size_t)VPAD * 512 * 2, stream);
    cvt_bf16<<<(VOCAB * 512 / 4 + 255) / 256, 256, 0, stream>>>(out_w, wv, VOCAB * 512);

    embed_kernel<<<NTOK, 128, 0, stream>>>(x, embed, ep_w, ep_b, h);

    for (int l = 0; l < NLAYER; ++l) {
        cvt_layer<<<3072, 256, 0, stream>>>(
            in_w + (size_t)l * 786432, op_w + (size_t)l * 262144,
            f1_w + (size_t)l * 1048576, f2_w + (size_t)l * 1048576,
            wq, wo, w1, w2);

        ln_kernel<<<NTOK / 4, 256, 0, stream>>>(h, ln1_w + l * 512, ln1_b + l * 512, g);
        gemm_t<128><<<dim3(64, 12), 256, 0, stream>>>(g, wq, in_b + l * 1536, nullptr,
                                                      nullptr, qkvb, vT, NTOK, 1536, 512, 0);
        attn_mfma<<<dim3(SEQ / 128, 64), 512, 0, stream>>>(qkvb, vT, g);
        gemm_k64<<<dim3(64, 8), 256, 0, stream>>>(g, wo, op_b + l * 512, h,
                                                  h, nullptr, NTOK, 512, 512, 2);
        ln_kernel<<<NTOK / 4, 256, 0, stream>>>(h, ln2_w + l * 512, ln2_b + l * 512, g);
        gemm_n256<<<dim3(64, 8), 256, 0, stream>>>(g, w1, f1_b + l * 2048,
                                                   nullptr, big, NTOK, 2048, 512, 1);
        gemm_k64<<<dim3(64, 8), 256, 0, stream>>>(big, w2, f2_b + l * 512, h,
                                                  h, (l == NLAYER - 1) ? hb : nullptr,
                                                  NTOK, 512, 2048, 2);
    }

    gemm_k64<<<dim3(64, 5), 256, 0, stream>>>(hb, wv, nullptr, nullptr,
                                              out, nullptr, NTOK, VOCAB, 512, 0);
}

// Round 19
// 1298.704 us; speedup vs baseline: 1.1250x; 1.1250x over previous
//
#include <hip/hip_runtime.h>
#include <hip/hip_bf16.h>

#define D_MODEL 512
#define NHEAD   8
#define DHEAD   64
#define SEQ     1024
#define NBATCH  8
#define NTOK    8192
#define DFF_N   2048
#define NLAYER  8
#define VOCAB   258
#define VPAD    384

typedef float f32x4 __attribute__((ext_vector_type(4)));
typedef short s16x8 __attribute__((ext_vector_type(8)));

__device__ __forceinline__ ushort f2b(float f) {
    union { float f; unsigned u; } v; v.f = f;
    unsigned r = (v.u + 0x7fffu + ((v.u >> 16) & 1u)) >> 16;
    return (ushort)r;
}
__device__ __forceinline__ float gelu_f(float x) {
    return 0.5f * x * (1.0f + erff(x * 0.70710678118654752f));
}
__device__ __forceinline__ void gl_lds16(const void* g, void* l) {
    __builtin_amdgcn_global_load_lds(
        (const __attribute__((address_space(1))) void*)g,
        (__attribute__((address_space(3))) void*)l, 16, 0, 0);
}
__device__ __forceinline__ float exp2_fast(float x) {
    float r; asm("v_exp_f32 %0, %1" : "=v"(r) : "v"(x)); return r;
}
__device__ __forceinline__ unsigned cvtpk(float lo, float hi) {
    unsigned r; asm("v_cvt_pk_bf16_f32 %0, %1, %2" : "=v"(r) : "v"(lo), "v"(hi)); return r;
}

// ---------------- f32 -> bf16 convert (single region) ----------------
__global__ __launch_bounds__(256) void cvt_bf16(
    const float* __restrict__ in, ushort* __restrict__ out, int n)
{
    int i = (blockIdx.x * 256 + threadIdx.x) << 2;
    if (i >= n) return;
    float4 v = *(const float4*)(in + i);
    ushort4 o;
    o.x = f2b(v.x); o.y = f2b(v.y); o.z = f2b(v.z); o.w = f2b(v.w);
    *(ushort4*)(out + i) = o;
}

// ---------------- per-layer 4-region weight convert (1 launch) ----------------
__global__ __launch_bounds__(256) void cvt_layer(
    const float* __restrict__ s0, const float* __restrict__ s1,
    const float* __restrict__ s2, const float* __restrict__ s3,
    ushort* __restrict__ d0, ushort* __restrict__ d1,
    ushort* __restrict__ d2, ushort* __restrict__ d3)
{
    int i = (blockIdx.x * 256 + threadIdx.x) << 2;
    const float* s; ushort* d; int off;
    if (i < 786432)        { s = s0; d = d0; off = i; }
    else if (i < 1048576)  { s = s1; d = d1; off = i - 786432; }
    else if (i < 2097152)  { s = s2; d = d2; off = i - 1048576; }
    else                   { s = s3; d = d3; off = i - 2097152; }
    float4 v = *(const float4*)(s + off);
    ushort4 o;
    o.x = f2b(v.x); o.y = f2b(v.y); o.z = f2b(v.z); o.w = f2b(v.w);
    *(ushort4*)(d + off) = o;
}

// ---------------- entropy features + embedding (f32 out) ----------------
__global__ __launch_bounds__(128) void embed_kernel(
    const int* __restrict__ x, const float* __restrict__ embed,
    const float* __restrict__ ep_w, const float* __restrict__ ep_b,
    float* __restrict__ h)
{
    int t = blockIdx.x;
    int pos = t & (SEQ - 1);
    float ent = 0.0f;
    if (pos <= SEQ - 8) {
        int v[8];
        #pragma unroll
        for (int i = 0; i < 8; i++) v[i] = x[t + i];
        float s = 0.0f;
        #pragma unroll
        for (int i = 0; i < 8; i++) {
            int c = 0;
            #pragma unroll
            for (int j = 0; j < 8; j++) c += (v[j] == v[i]) ? 1 : 0;
            s += log2f((float)c);
        }
        ent = 3.0f - 0.125f * s;
    }
    int tok = x[t];
    int d = threadIdx.x << 2;
    float e[4], w[4], bb[4], r[4];
    *(float4*)e  = *(const float4*)(embed + (size_t)tok * D_MODEL + d);
    *(float4*)w  = *(const float4*)(ep_w + d);
    *(float4*)bb = *(const float4*)(ep_b + d);
    #pragma unroll
    for (int j = 0; j < 4; j++) r[j] = e[j] + ent * w[j] + bb[j];
    *(float4*)(h + (size_t)t * D_MODEL + d) = *(float4*)r;
}

// ---------------- LayerNorm: f32 in -> bf16 out ----------------
__global__ __launch_bounds__(256) void ln_kernel(
    const float* __restrict__ in, const float* __restrict__ w,
    const float* __restrict__ b, ushort* __restrict__ out)
{
    int wid = threadIdx.x >> 6, lane = threadIdx.x & 63;
    int t = (blockIdx.x << 2) + wid;
    const float* row = in + (size_t)t * D_MODEL;
    float a[8];
    *(float4*)(a)     = *(const float4*)(row + (lane << 2));
    *(float4*)(a + 4) = *(const float4*)(row + 256 + (lane << 2));
    float s = 0.f;
    #pragma unroll
    for (int j = 0; j < 8; j++) s += a[j];
    #pragma unroll
    for (int o = 1; o < 64; o <<= 1) s += __shfl_xor(s, o);
    float mu = s * (1.0f / 512.0f);
    float vs = 0.f;
    #pragma unroll
    for (int j = 0; j < 8; j++) { float d0 = a[j] - mu; vs += d0 * d0; }
    #pragma unroll
    for (int o = 1; o < 64; o <<= 1) vs += __shfl_xor(vs, o);
    float inv = rsqrtf(vs * (1.0f / 512.0f) + 1e-5f);
    float ww[8], bbv[8];
    *(float4*)(ww)      = *(const float4*)(w + (lane << 2));
    *(float4*)(ww + 4)  = *(const float4*)(w + 256 + (lane << 2));
    *(float4*)(bbv)     = *(const float4*)(b + (lane << 2));
    *(float4*)(bbv + 4) = *(const float4*)(b + 256 + (lane << 2));
    ushort* orow = out + (size_t)t * D_MODEL;
    ushort4 o1, o2;
    o1.x = f2b((a[0] - mu) * inv * ww[0] + bbv[0]);
    o1.y = f2b((a[1] - mu) * inv * ww[1] + bbv[1]);
    o1.z = f2b((a[2] - mu) * inv * ww[2] + bbv[2]);
    o1.w = f2b((a[3] - mu) * inv * ww[3] + bbv[3]);
    o2.x = f2b((a[4] - mu) * inv * ww[4] + bbv[4]);
    o2.y = f2b((a[5] - mu) * inv * ww[5] + bbv[5]);
    o2.z = f2b((a[6] - mu) * inv * ww[6] + bbv[6]);
    o2.w = f2b((a[7] - mu) * inv * ww[7] + bbv[7]);
    *(ushort4*)(orow + (lane << 2))       = o1;
    *(ushort4*)(orow + 256 + (lane << 2)) = o2;
}

// ---------------- bf16 MFMA GEMM, BN in {128,64}, BK=32 (round-16) ----------
// 3-buffer counted-vmcnt pipeline + chunk-XOR swizzle + T1 XCD remap.
template<int BN>
__global__ __launch_bounds__(256) void gemm_t(
    const ushort* __restrict__ A, const ushort* __restrict__ Bw,
    const float* __restrict__ bias, const float* __restrict__ resid,
    float* __restrict__ Cf, ushort* __restrict__ Cb, ushort* __restrict__ Vtr,
    int M, int N, int K, int fuse)
{
    constexpr int NF = BN / 32;
    constexpr int EPW = BN + 4;
    __shared__ ushort SMEM[3 * 4096 + 3 * BN * 32];
    ushort* As0 = SMEM;                         // [3][4096]
    ushort* Bs0 = SMEM + 12288;                 // [3][BN*32]
    const int tid = threadIdx.x;
    const int l = tid & 63, w = tid >> 6;
    const int p  = blockIdx.y * gridDim.x + blockIdx.x;
    const int bx = ((p & 7) << 3) + ((p >> 3) & 7);
    const int by = p >> 6;
    const int m0 = bx << 7, n0 = by * BN;
    const int wrn = (w >> 1) << 6;
    const int wcn = (w & 1) * (BN / 2);
    const int fm = l & 15;
    const int soff = (((l & 3) ^ ((l >> 3) & 3)) << 3);
    const int foff = (((l >> 4) ^ ((fm >> 1) & 3)) << 3);
    f32x4 acc[4][NF] = {};

    const ushort* ga0 = A + (size_t)(m0 + (w << 5) + (l >> 2)) * K + soff;
    const ushort* ga1 = ga0 + (size_t)16 * K;
    const ushort* gb0;
    const ushort* gb1 = nullptr;
    if constexpr (BN == 128) {
        gb0 = Bw + (size_t)(n0 + (w << 5) + (l >> 2)) * K + soff;
        gb1 = gb0 + (size_t)16 * K;
    } else {
        gb0 = Bw + (size_t)(n0 + (w << 4) + (l >> 2)) * K + soff;
    }

    const int nk = K >> 5;
    auto stage = [&](int buf, int ko) {
        gl_lds16(ga0 + ko, As0 + buf * 4096 + (w << 10));
        gl_lds16(ga1 + ko, As0 + buf * 4096 + (w << 10) + 512);
        if constexpr (BN == 128) {
            gl_lds16(gb0 + ko, Bs0 + buf * (BN * 32) + (w << 10));
            gl_lds16(gb1 + ko, Bs0 + buf * (BN * 32) + (w << 10) + 512);
        } else {
            gl_lds16(gb0 + ko, Bs0 + buf * (BN * 32) + (w << 9));
        }
    };

    stage(0, 0);
    stage(1, 32);
    int cur = 0;
    for (int kt = 0; kt < nk; ++kt) {
        if (kt + 1 < nk) {
            if constexpr (BN == 128) asm volatile("s_waitcnt vmcnt(4)" ::: "memory");
            else                     asm volatile("s_waitcnt vmcnt(3)" ::: "memory");
        } else {
            asm volatile("s_waitcnt vmcnt(0)" ::: "memory");
        }
        asm volatile("s_barrier" ::: "memory");
        __builtin_amdgcn_sched_barrier(0);
        {
            int nxt = cur + 2; if (nxt >= 3) nxt -= 3;
            if (kt + 2 < nk) stage(nxt, (kt + 2) << 5);
        }
        s16x8 af[4], bf[NF];
        #pragma unroll
        for (int x = 0; x < 4; ++x)
            af[x] = *(const s16x8*)&As0[cur * 4096 + (wrn + (x << 4) + fm) * 32 + foff];
        #pragma unroll
        for (int y = 0; y < NF; ++y)
            bf[y] = *(const s16x8*)&Bs0[cur * (BN * 32) + (wcn + (y << 4) + fm) * 32 + foff];
        #pragma unroll
        for (int x = 0; x < 4; ++x)
            #pragma unroll
            for (int y = 0; y < NF; ++y)
                acc[x][y] = __builtin_amdgcn_mfma_f32_16x16x32_bf16(
                    af[x], bf[y], acc[x][y], 0, 0, 0);
        cur = (cur == 2) ? 0 : cur + 1;
    }
    __syncthreads();

    const float qs = (Vtr && n0 < 512) ? 0.18033688011112042f : 1.0f;
    const bool vblk = (Vtr != nullptr) && (n0 >= 1024);

    if (Cb != nullptr || vblk) {
        float* Ep = (float*)SMEM;
        const int lrw = ((w >> 1) << 4) + ((l >> 4) << 2);
        #pragma unroll
        for (int x = 0; x < 4; ++x) {
            __syncthreads();
            #pragma unroll
            for (int y = 0; y < NF; ++y) {
                const int c = wcn + (y << 4) + fm;
                const float bv = bias ? bias[n0 + c] : 0.f;
                #pragma unroll
                for (int i = 0; i < 4; ++i) {
                    float v = acc[x][y][i] + bv;
                    v *= qs;
                    if (fuse == 1) v = gelu_f(v);
                    Ep[(lrw + i) * EPW + c] = v;
                }
            }
            __syncthreads();
            if (vblk) {
                const int c = tid & 127;
                const int run = tid >> 7;
                const int colg = (n0 - 1024) + c;
                const int hh = colg >> 6, dd = colg & 63;
                float v16[16];
                #pragma unroll
                for (int j = 0; j < 16; ++j)
                    v16[j] = Ep[((run << 4) + j) * EPW + c];
                unsigned pk[8];
                #pragma unroll
                for (int j = 0; j < 8; ++j) pk[j] = cvtpk(v16[2 * j], v16[2 * j + 1]);
                ushort* dst = Vtr + ((size_t)(((m0 >> 10) << 3) + hh) * 64 + dd) * 1024
                              + (m0 & 1023) + (run << 6) + (x << 4);
                *(uint4*)dst       = *(uint4*)(pk);
                *(uint4*)(dst + 8) = *(uint4*)(pk + 4);
            } else {
                constexpr int TPR = BN / 8;
                constexpr int RPP = 256 / TPR;
                constexpr int NP = 32 / RPP;
                #pragma unroll
                for (int p2 = 0; p2 < NP; ++p2) {
                    const int lr = p2 * RPP + (tid / TPR);
                    const int cg = (tid % TPR) << 3;
                    const int grow = m0 + ((lr >> 4) << 6) + (x << 4) + (lr & 15);
                    const int gcol = n0 + cg;
                    float v8[8];
                    *(float4*)(v8)     = *(float4*)&Ep[lr * EPW + cg];
                    *(float4*)(v8 + 4) = *(float4*)&Ep[lr * EPW + cg + 4];
                    if (fuse == 2) {
                        float4 r1 = *(const float4*)&resid[(size_t)grow * N + gcol];
                        float4 r2 = *(const float4*)&resid[(size_t)grow * N + gcol + 4];
                        v8[0] += r1.x; v8[1] += r1.y; v8[2] += r1.z; v8[3] += r1.w;
                        v8[4] += r2.x; v8[5] += r2.y; v8[6] += r2.z; v8[7] += r2.w;
                    }
                    if (Cf) {
                        *(float4*)&Cf[(size_t)grow * N + gcol]     = *(float4*)v8;
                        *(float4*)&Cf[(size_t)grow * N + gcol + 4] = *(float4*)(v8 + 4);
                    }
                    unsigned pk[4];
                    pk[0] = cvtpk(v8[0], v8[1]); pk[1] = cvtpk(v8[2], v8[3]);
                    pk[2] = cvtpk(v8[4], v8[5]); pk[3] = cvtpk(v8[6], v8[7]);
                    *(uint4*)&Cb[(size_t)grow * N + gcol] = *(uint4*)pk;
                }
            }
        }
        return;
    }

    const int col0 = n0 + wcn + fm;
    const int row0 = m0 + wrn + ((l >> 4) << 2);
    #pragma unroll
    for (int x = 0; x < 4; ++x) {
        #pragma unroll
        for (int y = 0; y < NF; ++y) {
            int col = col0 + (y << 4);
            if (col >= N) continue;
            float bv = bias ? bias[col] : 0.f;
            #pragma unroll
            for (int i = 0; i < 4; ++i) {
                int row = row0 + (x << 4) + i;
                float v = acc[x][y][i] + bv;
                if (fuse == 1) v = gelu_f(v);
                else if (fuse == 2) v += resid[(size_t)row * N + col];
                Cf[(size_t)row * N + col] = v;
            }
        }
    }
}

// ---------------- bf16 MFMA GEMM, BM=128 x BN=64 x BK=64 (round-17) --------
__global__ __launch_bounds__(256) void gemm_k64(
    const ushort* __restrict__ A, const ushort* __restrict__ Bw,
    const float* __restrict__ bias, const float* __restrict__ resid,
    float* __restrict__ Cf, ushort* __restrict__ Cb,
    int M, int N, int K, int fuse)
{
    constexpr int EPW = 68;
    __shared__ ushort SMEM[3 * 8192 + 3 * 4096];
    ushort* As0 = SMEM;
    ushort* Bs0 = SMEM + 24576;
    const int tid = threadIdx.x;
    const int l = tid & 63, w = tid >> 6;
    const int p  = blockIdx.y * gridDim.x + blockIdx.x;
    const int bx = ((p & 7) << 3) + ((p >> 3) & 7);
    const int by = p >> 6;
    const int m0 = bx << 7, n0 = by << 6;
    const int wrn = (w >> 1) << 6;
    const int wcn = (w & 1) << 5;
    const int fm = l & 15, fk = l >> 4;
    f32x4 acc[4][2] = {};

    const int srow = (w << 3) + (l >> 3);
    const int cch = ((l & 7) ^ (l >> 3)) << 3;
    const ushort* gaP0 = A + (size_t)(m0 + srow) * K + cch;
    const ushort* gbP0 = Bw + (size_t)(n0 + srow) * K + cch;

    const int foff0 = (((0 << 2) + fk) ^ (fm & 7)) << 3;
    const int foff1 = (((1 << 2) + fk) ^ (fm & 7)) << 3;

    const int nk = K >> 6;
    auto stage = [&](int buf, int ko) {
        #pragma unroll
        for (int p2 = 0; p2 < 4; ++p2)
            gl_lds16(gaP0 + (size_t)(p2 << 5) * K + ko,
                     As0 + buf * 8192 + (p2 << 11) + (w << 9));
        #pragma unroll
        for (int p2 = 0; p2 < 2; ++p2)
            gl_lds16(gbP0 + (size_t)(p2 << 5) * K + ko,
                     Bs0 + buf * 4096 + (p2 << 11) + (w << 9));
    };

    stage(0, 0);
    stage(1, 64);
    int cur = 0;
    for (int kt = 0; kt < nk; ++kt) {
        if (kt + 1 < nk) asm volatile("s_waitcnt vmcnt(6)" ::: "memory");
        else             asm volatile("s_waitcnt vmcnt(0)" ::: "memory");
        asm volatile("s_barrier" ::: "memory");
        __builtin_amdgcn_sched_barrier(0);
        {
            int nxt = cur + 2; if (nxt >= 3) nxt -= 3;
            if (kt + 2 < nk) stage(nxt, (kt + 2) << 6);
        }
        {
            s16x8 af[4], bf[2];
            #pragma unroll
            for (int x = 0; x < 4; ++x)
                af[x] = *(const s16x8*)&As0[cur * 8192 + (wrn + (x << 4) + fm) * 64 + foff0];
            #pragma unroll
            for (int y = 0; y < 2; ++y)
                bf[y] = *(const s16x8*)&Bs0[cur * 4096 + (wcn + (y << 4) + fm) * 64 + foff0];
            #pragma unroll
            for (int x = 0; x < 4; ++x)
                #pragma unroll
                for (int y = 0; y < 2; ++y)
                    acc[x][y] = __builtin_amdgcn_mfma_f32_16x16x32_bf16(
                        af[x], bf[y], acc[x][y], 0, 0, 0);
        }
        {
            s16x8 af[4], bf[2];
            #pragma unroll
            for (int x = 0; x < 4; ++x)
                af[x] = *(const s16x8*)&As0[cur * 8192 + (wrn + (x << 4) + fm) * 64 + foff1];
            #pragma unroll
            for (int y = 0; y < 2; ++y)
                bf[y] = *(const s16x8*)&Bs0[cur * 4096 + (wcn + (y << 4) + fm) * 64 + foff1];
            #pragma unroll
            for (int x = 0; x < 4; ++x)
                #pragma unroll
                for (int y = 0; y < 2; ++y)
                    acc[x][y] = __builtin_amdgcn_mfma_f32_16x16x32_bf16(
                        af[x], bf[y], acc[x][y], 0, 0, 0);
        }
        cur = (cur == 2) ? 0 : cur + 1;
    }
    __syncthreads();

    if (Cb != nullptr) {
        float* Ep = (float*)SMEM;
        const int lrw = ((w >> 1) << 4) + ((l >> 4) << 2);
        #pragma unroll
        for (int x = 0; x < 4; ++x) {
            __syncthreads();
            #pragma unroll
            for (int y = 0; y < 2; ++y) {
                const int c = wcn + (y << 4) + fm;
                const float bv = bias ? bias[n0 + c] : 0.f;
                #pragma unroll
                for (int i = 0; i < 4; ++i) {
                    float v = acc[x][y][i] + bv;
                    if (fuse == 1) v = gelu_f(v);
                    Ep[(lrw + i) * EPW + c] = v;
                }
            }
            __syncthreads();
            {
                const int lr = tid >> 3;
                const int cg = (tid & 7) << 3;
                const int grow = m0 + ((lr >> 4) << 6) + (x << 4) + (lr & 15);
                const int gcol = n0 + cg;
                float v8[8];
                *(float4*)(v8)     = *(float4*)&Ep[lr * EPW + cg];
                *(float4*)(v8 + 4) = *(float4*)&Ep[lr * EPW + cg + 4];
                if (fuse == 2) {
                    float4 r1 = *(const float4*)&resid[(size_t)grow * N + gcol];
                    float4 r2 = *(const float4*)&resid[(size_t)grow * N + gcol + 4];
                    v8[0] += r1.x; v8[1] += r1.y; v8[2] += r1.z; v8[3] += r1.w;
                    v8[4] += r2.x; v8[5] += r2.y; v8[6] += r2.z; v8[7] += r2.w;
                }
                if (Cf) {
                    *(float4*)&Cf[(size_t)grow * N + gcol]     = *(float4*)v8;
                    *(float4*)&Cf[(size_t)grow * N + gcol + 4] = *(float4*)(v8 + 4);
                }
                unsigned pk[4];
                pk[0] = cvtpk(v8[0], v8[1]); pk[1] = cvtpk(v8[2], v8[3]);
                pk[2] = cvtpk(v8[4], v8[5]); pk[3] = cvtpk(v8[6], v8[7]);
                *(uint4*)&Cb[(size_t)grow * N + gcol] = *(uint4*)pk;
            }
        }
        return;
    }

    const int col0 = n0 + wcn + fm;
    const int row0 = m0 + wrn + ((l >> 4) << 2);
    #pragma unroll
    for (int x = 0; x < 4; ++x) {
        #pragma unroll
        for (int y = 0; y < 2; ++y) {
            int col = col0 + (y << 4);
            if (col >= N) continue;
            float bv = bias ? bias[col] : 0.f;
            #pragma unroll
            for (int i = 0; i < 4; ++i) {
                int row = row0 + (x << 4) + i;
                float v = acc[x][y][i] + bv;
                if (fuse == 1) v = gelu_f(v);
                else if (fuse == 2) v += resid[(size_t)row * N + col];
                Cf[(size_t)row * N + col] = v;
            }
        }
    }
}

// ---------------- bf16 MFMA flash attention v7 (round-14, 2-buffer) ---------
__global__ __launch_bounds__(512) void attn_mfma(
    const ushort* __restrict__ qkv, const ushort* __restrict__ vT,
    ushort* __restrict__ out)
{
    __shared__ ushort Ks[2][4096];
    __shared__ ushort Vs[2][4096];
    const int tid = threadIdx.x;
    const int l = tid & 63, w = tid >> 6;
    const int p = blockIdx.y * gridDim.x + blockIdx.x;
    const int bh = ((p & 7) << 3) + (p >> 6);
    const int q0 = ((p >> 3) & 7) << 7;
    const int b = bh >> 3, h = bh & 7;
    const ushort* base = qkv + (size_t)b * SEQ * 1536 + h * 64;
    const ushort* kg = base + 512;
    const ushort* vg = vT + ((size_t)bh << 16);
    const int fm = l & 15, fk = l >> 4;

    s16x8 qf[2];
    {
        const ushort* qrow = base + (size_t)(q0 + (w << 4) + fm) * 1536 + (fk << 3);
        qf[0] = *(const s16x8*)qrow;
        qf[1] = *(const s16x8*)(qrow + 32);
    }
    s16x8 ones_f;
    #pragma unroll
    for (int j = 0; j < 8; ++j) ones_f[j] = (short)0x3F80;

    f32x4 accO[4] = {};
    f32x4 accL = {};

    const int srow = (w << 3) + (l >> 3);
    const int cch = ((l & 7) ^ (l >> 3)) << 3;
    const ushort* kga = kg + (size_t)srow * 1536 + cch;
    const ushort* vga = vg + (size_t)srow * 1024 + cch;

    int fidx[2][4];
    #pragma unroll
    for (int ks = 0; ks < 2; ++ks)
        #pragma unroll
        for (int n = 0; n < 4; ++n)
            fidx[ks][n] = (((n << 4) + fm) << 6) + ((((ks << 2) + fk) ^ (l & 7)) << 3);

    const int srcA = ((fk & 1) << 5) + fm;
    const int srcB = srcA + 16;
    const bool hiN = (fk >> 1) != 0;

    #define STAGE(buf, kt)                                                    \
        do {                                                                  \
            gl_lds16(kga + (size_t)((kt) << 6) * 1536, &Ks[buf][w << 9]);     \
            gl_lds16(vga + ((kt) << 6), &Vs[buf][w << 9]);                    \
        } while (0)

    STAGE(0, 0);
    asm volatile("s_waitcnt vmcnt(0)" ::: "memory");
    __builtin_amdgcn_s_barrier();

    int cur = 0;
    for (int kt = 0; kt < SEQ / 64; ++kt) {
        if (kt + 1 < SEQ / 64) STAGE(cur ^ 1, kt + 1);
        __builtin_amdgcn_sched_barrier(0);

        f32x4 s[4] = {};
        __builtin_amdgcn_s_setprio(1);
        #pragma unroll
        for (int ks = 0; ks < 2; ++ks)
            #pragma unroll
            for (int n = 0; n < 4; ++n) {
                s16x8 kf = *(const s16x8*)&Ks[cur][fidx[ks][n]];
                s[n] = __builtin_amdgcn_mfma_f32_16x16x32_bf16(kf, qf[ks], s[n], 0, 0, 0);
            }
        __builtin_amdgcn_s_setprio(0);

        unsigned pk0[2], pk1[2], pk2[2], pk3[2];
        pk0[0] = cvtpk(exp2_fast(s[0][0]), exp2_fast(s[0][1]));
        pk0[1] = cvtpk(exp2_fast(s[0][2]), exp2_fast(s[0][3]));
        pk1[0] = cvtpk(exp2_fast(s[1][0]), exp2_fast(s[1][1]));
        pk1[1] = cvtpk(exp2_fast(s[1][2]), exp2_fast(s[1][3]));
        pk2[0] = cvtpk(exp2_fast(s[2][0]), exp2_fast(s[2][1]));
        pk2[1] = cvtpk(exp2_fast(s[2][2]), exp2_fast(s[2][3]));
        pk3[0] = cvtpk(exp2_fast(s[3][0]), exp2_fast(s[3][1]));
        pk3[1] = cvtpk(exp2_fast(s[3][2]), exp2_fast(s[3][3]));

        #pragma unroll
        for (int ks = 0; ks < 2; ++ks) {
            unsigned u0 = ks ? pk2[0] : pk0[0], u1 = ks ? pk2[1] : pk0[1];
            unsigned v0 = ks ? pk3[0] : pk1[0], v1 = ks ? pk3[1] : pk1[1];
            unsigned a0 = __shfl((int)u0, srcA), b0 = __shfl((int)v0, srcA);
            unsigned a1 = __shfl((int)u1, srcA), b1 = __shfl((int)v1, srcA);
            unsigned a2 = __shfl((int)u0, srcB), b2 = __shfl((int)v0, srcB);
            unsigned a3 = __shfl((int)u1, srcB), b3 = __shfl((int)v1, srcB);
            union { unsigned u[4]; s16x8 v; } pb;
            pb.u[0] = hiN ? b0 : a0;
            pb.u[1] = hiN ? b1 : a1;
            pb.u[2] = hiN ? b2 : a2;
            pb.u[3] = hiN ? b3 : a3;
            __builtin_amdgcn_s_setprio(1);
            #pragma unroll
            for (int n = 0; n < 4; ++n) {
                s16x8 vf = *(const s16x8*)&Vs[cur][fidx[ks][n]];
                accO[n] = __builtin_amdgcn_mfma_f32_16x16x32_bf16(vf, pb.v, accO[n], 0, 0, 0);
            }
            accL = __builtin_amdgcn_mfma_f32_16x16x32_bf16(ones_f, pb.v, accL, 0, 0, 0);
            __builtin_amdgcn_s_setprio(0);
        }

        asm volatile("s_waitcnt vmcnt(0)" ::: "memory");
        __builtin_amdgcn_s_barrier();
        __builtin_amdgcn_sched_barrier(0);
        cur ^= 1;
    }
    #undef STAGE

    const int q = q0 + (w << 4) + fm;
    float inv = 1.0f / accL[0];
    ushort* obase = out + ((size_t)(b * SEQ + q)) * 512 + h * 64 + (fk << 2);
    #pragma unroll
    for (int n = 0; n < 4; ++n) {
        ushort4 o;
        o.x = f2b(accO[n][0] * inv);
        o.y = f2b(accO[n][1] * inv);
        o.z = f2b(accO[n][2] * inv);
        o.w = f2b(accO[n][3] * inv);
        *(ushort4*)(obase + (n << 4)) = o;
    }
}

extern "C" void kernel_launch(void* const* d_in, const int* in_sizes, int n_in,
                              void* d_out, int out_size, void* d_ws, size_t ws_size,
                              hipStream_t stream) {
    const int*   x     = (const int*)  d_in[0];
    const float* embed = (const float*)d_in[1];
    const float* ep_w  = (const float*)d_in[2];
    const float* ep_b  = (const float*)d_in[3];
    const float* in_w  = (const float*)d_in[4];
    const float* in_b  = (const float*)d_in[5];
    const float* op_w  = (const float*)d_in[6];
    const float* op_b  = (const float*)d_in[7];
    const float* ln1_w = (const float*)d_in[8];
    const float* ln1_b = (const float*)d_in[9];
    const float* ln2_w = (const float*)d_in[10];
    const float* ln2_b = (const float*)d_in[11];
    const float* f1_w  = (const float*)d_in[12];
    const float* f1_b  = (const float*)d_in[13];
    const float* f2_w  = (const float*)d_in[14];
    const float* f2_b  = (const float*)d_in[15];
    const float* out_w = (const float*)d_in[16];
    float* out = (float*)d_out;

    char* ws = (char*)d_ws;
    float*  h    = (float*) (ws + 0);
    ushort* g    = (ushort*)(ws + 16777216);
    ushort* big  = (ushort*)(ws + 25165824);
    ushort* qkvb = big;
    ushort* hb   = (ushort*)(ws + 58720256);
    ushort* wq   = (ushort*)(ws + 67108864);
    ushort* wo   = (ushort*)(ws + 68681728);
    ushort* w1   = (ushort*)(ws + 69206016);
    ushort* w2   = (ushort*)(ws + 71303168);
    ushort* wv   = (ushort*)(ws + 73400320);
    ushort* vT   = (ushort*)(ws + 73793536);

    hipMemsetAsync(wv, 0, (size_t)VPAD * 512 * 2, stream);
    cvt_bf16<<<(VOCAB * 512 / 4 + 255) / 256, 256, 0, stream>>>(out_w, wv, VOCAB * 512);

    embed_kernel<<<NTOK, 128, 0, stream>>>(x, embed, ep_w, ep_b, h);

    for (int l = 0; l < NLAYER; ++l) {
        cvt_layer<<<3072, 256, 0, stream>>>(
            in_w + (size_t)l * 786432, op_w + (size_t)l * 262144,
            f1_w + (size_t)l * 1048576, f2_w + (size_t)l * 1048576,
            wq, wo, w1, w2);

        ln_kernel<<<NTOK / 4, 256, 0, stream>>>(h, ln1_w + l * 512, ln1_b + l * 512, g);
        gemm_t<128><<<dim3(64, 12), 256, 0, stream>>>(g, wq, in_b + l * 1536, nullptr,
                                                      nullptr, qkvb, vT, NTOK, 1536, 512, 0);
        attn_mfma<<<dim3(SEQ / 128, 64), 512, 0, stream>>>(qkvb, vT, g);
        gemm_k64<<<dim3(64, 8), 256, 0, stream>>>(g, wo, op_b + l * 512, h,
                                                  h, nullptr, NTOK, 512, 512, 2);
        ln_kernel<<<NTOK / 4, 256, 0, stream>>>(h, ln2_w + l * 512, ln2_b + l * 512, g);
        gemm_t<128><<<dim3(64, 16), 256, 0, stream>>>(g, w1, f1_b + l * 2048, nullptr,
                                                      nullptr, big, nullptr, NTOK, 2048, 512, 1);
        gemm_k64<<<dim3(64, 8), 256, 0, stream>>>(big, w2, f2_b + l * 512, h,
                                                  h, (l == NLAYER - 1) ? hb : nullptr,
                                                  NTOK, 512, 2048, 2);
    }

    gemm_k64<<<dim3(64, 5), 256, 0, stream>>>(hb, wv, nullptr, nullptr,
                                              out, nullptr, NTOK, VOCAB, 512, 0);
}